// Round 11
// baseline (93.119 us; speedup 1.0000x reference)
//
#include <hip/hip_runtime.h>
#include <math.h>

#define IMH 512
#define IMW 512
#define RB    32    // output rows per wave-band (R10: 16->32, halves y-halo traffic)
#define NBAND 16    // IMH / RB
#define NWC   10    // wave-columns: out width 56 each, c0 = 56*wc - 4
#define OUTW  56

__device__ __forceinline__ int reflect_i(int v, int n) {
    if (v < 0) v = -v;
    if (v >= n) v = 2 * n - 2 - v;
    return v;
}
// DPP wave shifts (VALU pipe). 0x138=wave_shr1 (lane i <- i-1), 0x130=wave_shl1
// (lane i <- i+1) — direction anchored by R4(shfl)==R6(dpp) identical results.
__device__ __forceinline__ float dpp_shr1(float x) {
    int i = __float_as_int(x);
    return __int_as_float(__builtin_amdgcn_update_dpp(i, i, 0x138, 0xF, 0xF, false));
}
__device__ __forceinline__ float dpp_shl1(float x) {
    int i = __float_as_int(x);
    return __int_as_float(__builtin_amdgcn_update_dpp(i, i, 0x130, 0xF, 0xF, false));
}

// One wave streams a 64-col x RB-row band; lane = column cx = c0+lane.
// YB: band touches top/bottom image rows. XB: wave touches left/right cols.
// Fully unrolled: ring rotations become register renames; emit guard folds.
template <bool YB, bool XB>
__device__ __forceinline__ void run_band(const float* __restrict__ p0,
                                         const float* __restrict__ p1,
                                         const float* __restrict__ p2,
                                         float* __restrict__ outp,
                                         int y0, int c0, int lane) {
    const float w0 = 0.05448868f, w1 = 0.24420134f, w2 = 0.40261995f;
    const int cx = c0 + lane;
    const int rx = XB ? reflect_i(cx, IMW) : cx;   // col reflect only at x-borders
    int ixm = lane - 1, ixp = lane + 1;
    if (XB) {
        ixm = (cx - 1 < 0 ? 0 : (cx - 1 >= IMW ? IMW - 1 : cx - 1)) - c0;
        ixp = (cx + 1 < 0 ? 0 : (cx + 1 >= IMW ? IMW - 1 : cx + 1)) - c0;
    }
    const bool storeok = (lane >= 4) && (lane < 60) &&
                         (!XB || (unsigned)cx < (unsigned)IMW);

    // rolling rings (renamed away under full unroll)
    float h0 = 0, h1 = 0, h2 = 0, h3 = 0;
    float b_1 = 0, b_0 = 0, bl_1 = 0, bl_0 = 0, br_1 = 0, br_0 = 0;
    float m_1 = 0, m_0 = 0, ml_1 = 0, ml_0 = 0, mr_1 = 0, mr_0 = 0;
    float gxp = 0, gyp = 0;

    auto process = [&](int yL, float gray, bool emit) {
        float gm1 = dpp_shr1(gray);
        float gm2 = dpp_shr1(gm1);
        float gp1 = dpp_shl1(gray);
        float gp2 = dpp_shl1(gp1);
        float hnew = w0 * (gm2 + gp2) + w1 * (gm1 + gp1) + w2 * gray;
        float bnew = w0 * (h0 + hnew) + w1 * (h1 + h3) + w2 * h2;
        float blnew, brnew;     // edge-clamped col neighbors of blurred
        if (XB) { blnew = __shfl(bnew, ixm); brnew = __shfl(bnew, ixp); }
        else    { blnew = dpp_shr1(bnew);    brnew = dpp_shl1(bnew); }
        int u = yL - 3;
        float ta = b_1, tla = bl_1, tra = br_1;       // row u-1
        float tb = bnew, tlb = blnew, trb = brnew;    // row u+1
        if (YB) {
            if (u == 0)       { ta = b_0; tla = bl_0; tra = br_0; }
            if (u == IMH - 1) { tb = b_0; tlb = bl_0; trb = br_0; }
        }
        float gx = (tra - tla) + 2.0f * (br_0 - bl_0) + (trb - tlb);
        float gy = (tlb - tla) + 2.0f * (tb - ta) + (trb - tra);
        float mnew = __builtin_amdgcn_sqrtf(gx * gx + gy * gy + 1e-6f);
        if (XB) { if ((unsigned)cx >= (unsigned)IMW) mnew = 0.0f; }  // NMS zero-pad
        float mlnew = dpp_shr1(mnew);
        float mrnew = dpp_shl1(mnew);
        if (emit) {            // compile-time under full unroll
            int s = yL - 4;
            float pm = m_1, pml = ml_1, pmr = mr_1;
            float nm = mnew, nml = mlnew, nmr = mrnew;
            if (YB) {
                if (s == 0)       { pm = 0; pml = 0; pmr = 0; }
                if (s == IMH - 1) { nm = 0; nml = 0; nmr = 0; }
            }
            float ax = fabsf(gxp), ay = fabsf(gyp);
            bool ew = (ay <= 0.41421356237f * ax);
            bool ns = (ay >= 2.41421356237f * ax);
            bool d1 = (gxp * gyp > 0.0f);
            float n1 = ew ? mr_0 : (ns ? nm : (d1 ? pmr : nmr));
            float n2 = ew ? ml_0 : (ns ? pm : (d1 ? nml : pml));
            float mag = m_0;
            float o = (mag > n1 && mag > n2) ? mag : 0.0f;
            if (storeok)
                __builtin_nontemporal_store(o, &outp[(size_t)s * IMW + cx]);
        }
        h0 = h1; h1 = h2; h2 = h3; h3 = hnew;
        b_1 = b_0;  b_0 = bnew;
        bl_1 = bl_0; bl_0 = blnew;
        br_1 = br_0; br_0 = brnew;
        m_1 = m_0;  m_0 = mnew;
        ml_1 = ml_0; ml_0 = mlnew;
        mr_1 = mr_0; mr_0 = mrnew;
        gxp = gx; gyp = gy;
    };

    // depth-2 A/B prefetch, rows yL = y0-4 .. y0+RB+3
    int ya = (YB ? reflect_i(y0 - 4, IMH) : (y0 - 4)) * IMW;
    float rA = p0[ya + rx], gA = p1[ya + rx], cA = p2[ya + rx];
    int yb = (YB ? reflect_i(y0 - 3, IMH) : (y0 - 3)) * IMW;
    float rB = p0[yb + rx], gB = p1[yb + rx], cB = p2[yb + rx];

    #pragma unroll
    for (int tt = 0; tt < (RB + 8) / 2; ++tt) {
        int yL = y0 - 4 + 2 * tt;
        float grayA = 0.1495f * rA + 0.2935f * gA + 0.057f * cA;
        if (tt < (RB + 8) / 2 - 1) {
            int yr = (YB ? reflect_i(yL + 2, IMH) : (yL + 2)) * IMW;
            rA = p0[yr + rx]; gA = p1[yr + rx]; cA = p2[yr + rx];
        }
        process(yL, grayA, tt >= 4);
        float grayB = 0.1495f * rB + 0.2935f * gB + 0.057f * cB;
        if (tt < (RB + 8) / 2 - 1) {
            int yr2 = (YB ? reflect_i(yL + 3, IMH) : (yL + 3)) * IMW;
            rB = p0[yr2 + rx]; gB = p1[yr2 + rx]; cB = p2[yr2 + rx];
        }
        process(yL + 1, grayB, tt >= 4);
    }
}

__global__ __launch_bounds__(256)
void canny_stream(const float* __restrict__ data, float* __restrict__ out) {
    const int lane = threadIdx.x & 63;
    const int wid  = (blockIdx.x << 2) + (threadIdx.x >> 6);
    const int wc   = wid % NWC;
    const int t2   = wid / NWC;
    const int band = t2 & (NBAND - 1);
    const int bat  = t2 >> 4;            // t2 / NBAND

    const int c0 = OUTW * wc - 4;
    const int y0 = band * RB;

    const size_t plane = (size_t)(IMH * IMW);
    const float* p0 = data + (size_t)bat * 3 * plane;
    const float* p1 = p0 + plane;
    const float* p2 = p1 + plane;
    float* outp = out + (size_t)bat * plane;

    const bool yb = (band == 0) || (band == NBAND - 1);
    const bool xb = (wc == 0) || (wc == NWC - 1);
    if (yb) {
        if (xb) run_band<true, true >(p0, p1, p2, outp, y0, c0, lane);
        else    run_band<true, false>(p0, p1, p2, outp, y0, c0, lane);
    } else {
        if (xb) run_band<false, true >(p0, p1, p2, outp, y0, c0, lane);
        else    run_band<false, false>(p0, p1, p2, outp, y0, c0, lane);
    }
}

extern "C" void kernel_launch(void* const* d_in, const int* in_sizes, int n_in,
                              void* d_out, int out_size, void* d_ws, size_t ws_size,
                              hipStream_t stream) {
    const float* data = (const float*)d_in[0];
    float* out = (float*)d_out;
    int B = in_sizes[0] / (3 * IMH * IMW);   // 16
    int blocks = (B * NBAND * NWC) / 4;      // 4 waves/block = 640 blocks, 2560 waves
    canny_stream<<<blocks, dim3(256, 1, 1), 0, stream>>>(data, out);
}

// Round 12
// 88.670 us; speedup vs baseline: 1.0502x; 1.0502x over previous
//
#include <hip/hip_runtime.h>
#include <math.h>

#define IMH 512
#define IMW 512
#define RB    16    // output rows per wave-band (R9 champion config)
#define NBAND 32    // IMH / RB
#define NWC   10    // wave-columns: out width 56 each, c0 = 56*wc - 4
#define OUTW  56

__device__ __forceinline__ int reflect_i(int v, int n) {
    if (v < 0) v = -v;
    if (v >= n) v = 2 * n - 2 - v;
    return v;
}
// DPP wave shifts (VALU pipe). 0x138=wave_shr1 (lane i <- i-1), 0x130=wave_shl1
// (lane i <- i+1) — direction anchored by R4(shfl)==R6(dpp) identical results.
__device__ __forceinline__ float dpp_shr1(float x) {
    int i = __float_as_int(x);
    return __int_as_float(__builtin_amdgcn_update_dpp(i, i, 0x138, 0xF, 0xF, false));
}
__device__ __forceinline__ float dpp_shl1(float x) {
    int i = __float_as_int(x);
    return __int_as_float(__builtin_amdgcn_update_dpp(i, i, 0x130, 0xF, 0xF, false));
}

// One wave streams a 64-col x RB-row band; lane = column cx = c0+lane.
// YB: band touches top/bottom image rows. XB: wave touches left/right cols.
template <bool YB, bool XB>
__device__ __forceinline__ void run_band(const float* __restrict__ p0,
                                         const float* __restrict__ p1,
                                         const float* __restrict__ p2,
                                         float* __restrict__ outp,
                                         int y0, int c0, int lane) {
    const float w0 = 0.05448868f, w1 = 0.24420134f, w2 = 0.40261995f;
    const int cx = c0 + lane;
    const int rx = XB ? reflect_i(cx, IMW) : cx;
    int ixm = lane - 1, ixp = lane + 1;
    if (XB) {
        ixm = (cx - 1 < 0 ? 0 : (cx - 1 >= IMW ? IMW - 1 : cx - 1)) - c0;
        ixp = (cx + 1 < 0 ? 0 : (cx + 1 >= IMW ? IMW - 1 : cx + 1)) - c0;
    }
    const bool storeok = (lane >= 4) && (lane < 60) &&
                         (!XB || (unsigned)cx < (unsigned)IMW);

    float h0 = 0, h1 = 0, h2 = 0, h3 = 0;
    float b_1 = 0, b_0 = 0, bl_1 = 0, bl_0 = 0, br_1 = 0, br_0 = 0;
    float m_1 = 0, m_0 = 0, ml_1 = 0, ml_0 = 0, mr_1 = 0, mr_0 = 0;
    float gxp = 0, gyp = 0;

    auto process = [&](int yL, float gray, bool emit) {
        float gm1 = dpp_shr1(gray);
        float gm2 = dpp_shr1(gm1);
        float gp1 = dpp_shl1(gray);
        float gp2 = dpp_shl1(gp1);
        float hnew = w0 * (gm2 + gp2) + w1 * (gm1 + gp1) + w2 * gray;
        float bnew = w0 * (h0 + hnew) + w1 * (h1 + h3) + w2 * h2;
        float blnew, brnew;
        if (XB) { blnew = __shfl(bnew, ixm); brnew = __shfl(bnew, ixp); }
        else    { blnew = dpp_shr1(bnew);    brnew = dpp_shl1(bnew); }
        int u = yL - 3;
        float ta = b_1, tla = bl_1, tra = br_1;
        float tb = bnew, tlb = blnew, trb = brnew;
        if (YB) {
            if (u == 0)       { ta = b_0; tla = bl_0; tra = br_0; }
            if (u == IMH - 1) { tb = b_0; tlb = bl_0; trb = br_0; }
        }
        float gx = (tra - tla) + 2.0f * (br_0 - bl_0) + (trb - tlb);
        float gy = (tlb - tla) + 2.0f * (tb - ta) + (trb - tra);
        float mnew = __builtin_amdgcn_sqrtf(gx * gx + gy * gy + 1e-6f);
        if (XB) { if ((unsigned)cx >= (unsigned)IMW) mnew = 0.0f; }
        float mlnew = dpp_shr1(mnew);
        float mrnew = dpp_shl1(mnew);
        if (emit) {
            int s = yL - 4;
            float pm = m_1, pml = ml_1, pmr = mr_1;
            float nm = mnew, nml = mlnew, nmr = mrnew;
            if (YB) {
                if (s == 0)       { pm = 0; pml = 0; pmr = 0; }
                if (s == IMH - 1) { nm = 0; nml = 0; nmr = 0; }
            }
            float ax = fabsf(gxp), ay = fabsf(gyp);
            bool ew = (ay <= 0.41421356237f * ax);
            bool ns = (ay >= 2.41421356237f * ax);
            bool d1 = (gxp * gyp > 0.0f);
            float n1 = ew ? mr_0 : (ns ? nm : (d1 ? pmr : nmr));
            float n2 = ew ? ml_0 : (ns ? pm : (d1 ? nml : pml));
            float mag = m_0;
            float o = (mag > n1 && mag > n2) ? mag : 0.0f;
            if (storeok)
                __builtin_nontemporal_store(o, &outp[(size_t)s * IMW + cx]);
        }
        h0 = h1; h1 = h2; h2 = h3; h3 = hnew;
        b_1 = b_0;  b_0 = bnew;
        bl_1 = bl_0; bl_0 = blnew;
        br_1 = br_0; br_0 = brnew;
        m_1 = m_0;  m_0 = mnew;
        ml_1 = ml_0; ml_0 = mlnew;
        mr_1 = mr_0; mr_0 = mrnew;
        gxp = gx; gyp = gy;
    };

    int ya = (YB ? reflect_i(y0 - 4, IMH) : (y0 - 4)) * IMW;
    float rA = p0[ya + rx], gA = p1[ya + rx], cA = p2[ya + rx];
    int yb = (YB ? reflect_i(y0 - 3, IMH) : (y0 - 3)) * IMW;
    float rB = p0[yb + rx], gB = p1[yb + rx], cB = p2[yb + rx];

    #pragma unroll
    for (int tt = 0; tt < (RB + 8) / 2; ++tt) {
        int yL = y0 - 4 + 2 * tt;
        float grayA = 0.1495f * rA + 0.2935f * gA + 0.057f * cA;
        if (tt < (RB + 8) / 2 - 1) {
            int yr = (YB ? reflect_i(yL + 2, IMH) : (yL + 2)) * IMW;
            rA = p0[yr + rx]; gA = p1[yr + rx]; cA = p2[yr + rx];
        }
        process(yL, grayA, tt >= 4);
        float grayB = 0.1495f * rB + 0.2935f * gB + 0.057f * cB;
        if (tt < (RB + 8) / 2 - 1) {
            int yr2 = (YB ? reflect_i(yL + 3, IMH) : (yL + 3)) * IMW;
            rB = p0[yr2 + rx]; gB = p1[yr2 + rx]; cB = p2[yr2 + rx];
        }
        process(yL + 1, grayB, tt >= 4);
    }
}

__global__ __launch_bounds__(256)
void canny_stream(const float* __restrict__ data, float* __restrict__ out) {
    const int lane = threadIdx.x & 63;
    // XCD-aware swizzle (R11): blocks with equal blockIdx%8 land on one XCD
    // (heuristic, perf-only). Give each XCD 2 whole batches and walk their
    // bands sequentially so adjacent bands / wave-columns (shared halo rows
    // and cols) execute temporally close on the SAME XCD -> halo re-reads hit
    // that XCD's L2 instead of duplicate HBM fetches.
    const int xcd = blockIdx.x & 7;            // 0..7
    const int seq = blockIdx.x >> 3;           // 0..159 per-XCD block sequence
    const int lw  = (seq << 2) | (threadIdx.x >> 6);   // 0..639 local wave
    const int wc   = lw % NWC;                 // 0..9
    const int t    = lw / NWC;                 // 0..63
    const int band = t & (NBAND - 1);          // 0..31
    const int bat  = (xcd << 1) | (t >> 5);    // 2 batches per XCD (B=16)

    const int c0 = OUTW * wc - 4;
    const int y0 = band * RB;

    const size_t plane = (size_t)(IMH * IMW);
    const float* p0 = data + (size_t)bat * 3 * plane;
    const float* p1 = p0 + plane;
    const float* p2 = p1 + plane;
    float* outp = out + (size_t)bat * plane;

    const bool yb = (band == 0) || (band == NBAND - 1);
    const bool xb = (wc == 0) || (wc == NWC - 1);
    if (yb) {
        if (xb) run_band<true, true >(p0, p1, p2, outp, y0, c0, lane);
        else    run_band<true, false>(p0, p1, p2, outp, y0, c0, lane);
    } else {
        if (xb) run_band<false, true >(p0, p1, p2, outp, y0, c0, lane);
        else    run_band<false, false>(p0, p1, p2, outp, y0, c0, lane);
    }
}

extern "C" void kernel_launch(void* const* d_in, const int* in_sizes, int n_in,
                              void* d_out, int out_size, void* d_ws, size_t ws_size,
                              hipStream_t stream) {
    const float* data = (const float*)d_in[0];
    float* out = (float*)d_out;
    int B = in_sizes[0] / (3 * IMH * IMW);   // 16
    int blocks = (B * NBAND * NWC) / 4;      // 1280 blocks, 5120 waves
    canny_stream<<<blocks, dim3(256, 1, 1), 0, stream>>>(data, out);
}

// Round 13
// 88.294 us; speedup vs baseline: 1.0546x; 1.0043x over previous
//
#include <hip/hip_runtime.h>
#include <math.h>

#define IMH 512
#define IMW 512
#define RB    16    // output rows per wave-band (champion config)
#define NBAND 32    // IMH / RB
#define NWC   10    // wave-columns: out width 56 each, c0 = 56*wc - 4
#define OUTW  56

__device__ __forceinline__ int reflect_i(int v, int n) {
    if (v < 0) v = -v;
    if (v >= n) v = 2 * n - 2 - v;
    return v;
}
// DPP wave shifts (VALU pipe). 0x138=wave_shr1 (lane i <- i-1), 0x130=wave_shl1.
__device__ __forceinline__ float dpp_shr1(float x) {
    int i = __float_as_int(x);
    return __int_as_float(__builtin_amdgcn_update_dpp(i, i, 0x138, 0xF, 0xF, false));
}
__device__ __forceinline__ float dpp_shl1(float x) {
    int i = __float_as_int(x);
    return __int_as_float(__builtin_amdgcn_update_dpp(i, i, 0x130, 0xF, 0xF, false));
}

// One wave streams a 64-col x RB-row band; lane = column cx = c0+lane.
// Fully unrolled; pipeline phases gated at compile time:
//   k<4: gray+hblur only; k>=4: +vblur; k>=6: +sobel/mag; k>=8: +NMS/store.
// Depth-4 row prefetch: 12 loads in flight, issued 4 steps (~500cyc) ahead.
template <bool YB, bool XB>
__device__ __forceinline__ void run_band(const float* __restrict__ p0,
                                         const float* __restrict__ p1,
                                         const float* __restrict__ p2,
                                         float* __restrict__ outp,
                                         int y0, int c0, int lane) {
    const float w0 = 0.05448868f, w1 = 0.24420134f, w2 = 0.40261995f;
    const int cx = c0 + lane;
    const int rx = XB ? reflect_i(cx, IMW) : cx;
    int ixm = lane - 1, ixp = lane + 1;
    if (XB) {
        ixm = (cx - 1 < 0 ? 0 : (cx - 1 >= IMW ? IMW - 1 : cx - 1)) - c0;
        ixp = (cx + 1 < 0 ? 0 : (cx + 1 >= IMW ? IMW - 1 : cx + 1)) - c0;
    }
    const bool storeok = (lane >= 4) && (lane < 60) &&
                         (!XB || (unsigned)cx < (unsigned)IMW);

    float h0 = 0, h1 = 0, h2 = 0, h3 = 0;
    float b_1 = 0, b_0 = 0, bl_1 = 0, bl_0 = 0, br_1 = 0, br_0 = 0;
    float m_1 = 0, m_0 = 0, ml_1 = 0, ml_0 = 0, mr_1 = 0, mr_0 = 0;
    float gxp = 0, gyp = 0;

    // depth-4 rolling load slots
    float rr[4], gg[4], bb[4];
    #pragma unroll
    for (int k = 0; k < 4; ++k) {
        int y = y0 - 4 + k;
        int yo = (YB ? reflect_i(y, IMH) : y) * IMW + rx;
        rr[k] = p0[yo]; gg[k] = p1[yo]; bb[k] = p2[yo];
    }

    #pragma unroll
    for (int k = 0; k < RB + 8; ++k) {
        const int yL = y0 - 4 + k;
        const int sl = k & 3;
        float gray = 0.1495f * rr[sl] + 0.2935f * gg[sl] + 0.057f * bb[sl];
        if (k + 4 < RB + 8) {     // refill slot 4 steps ahead of consumption
            int y = yL + 4;
            int yo = (YB ? reflect_i(y, IMH) : y) * IMW + rx;
            rr[sl] = p0[yo]; gg[sl] = p1[yo]; bb[sl] = p2[yo];
        }
        // gray + horizontal blur (every step; fills h-ring)
        float gm1 = dpp_shr1(gray);
        float gm2 = dpp_shr1(gm1);
        float gp1 = dpp_shl1(gray);
        float gp2 = dpp_shl1(gp1);
        float hnew = w0 * (gm2 + gp2) + w1 * (gm1 + gp1) + w2 * gray;

        float bnew = 0, blnew = 0, brnew = 0;
        if (k >= 4) {             // vertical blur -> row yL-2 (first needed row y0-2)
            bnew = w0 * (h0 + hnew) + w1 * (h1 + h3) + w2 * h2;
            if (XB) { blnew = __shfl(bnew, ixm); brnew = __shfl(bnew, ixp); }
            else    { blnew = dpp_shr1(bnew);    brnew = dpp_shl1(bnew); }
        }

        float mnew = 0, mlnew = 0, mrnew = 0, gx = 0, gy = 0;
        if (k >= 6) {             // sobel+mag -> row yL-3 (first needed row y0-1)
            int u = yL - 3;
            float ta = b_1, tla = bl_1, tra = br_1;
            float tb = bnew, tlb = blnew, trb = brnew;
            if (YB) {
                if (u == 0)       { ta = b_0; tla = bl_0; tra = br_0; }
                if (u == IMH - 1) { tb = b_0; tlb = bl_0; trb = br_0; }
            }
            gx = (tra - tla) + 2.0f * (br_0 - bl_0) + (trb - tlb);
            gy = (tlb - tla) + 2.0f * (tb - ta) + (trb - tra);
            mnew = __builtin_amdgcn_sqrtf(gx * gx + gy * gy + 1e-6f);
            if (XB) { if ((unsigned)cx >= (unsigned)IMW) mnew = 0.0f; }
            mlnew = dpp_shr1(mnew);
            mrnew = dpp_shl1(mnew);
        }

        if (k >= 8) {             // NMS + store row s = yL-4
            int s = yL - 4;
            float pm = m_1, pml = ml_1, pmr = mr_1;
            float nm = mnew, nml = mlnew, nmr = mrnew;
            if (YB) {
                if (s == 0)       { pm = 0; pml = 0; pmr = 0; }
                if (s == IMH - 1) { nm = 0; nml = 0; nmr = 0; }
            }
            float ax = fabsf(gxp), ay = fabsf(gyp);
            bool ew = (ay <= 0.41421356237f * ax);
            bool ns = (ay >= 2.41421356237f * ax);
            bool d1 = (gxp * gyp > 0.0f);
            float n1 = ew ? mr_0 : (ns ? nm : (d1 ? pmr : nmr));
            float n2 = ew ? ml_0 : (ns ? pm : (d1 ? nml : pml));
            float mag = m_0;
            float o = (mag > n1 && mag > n2) ? mag : 0.0f;
            if (storeok)
                __builtin_nontemporal_store(o, &outp[(size_t)s * IMW + cx]);
        }

        h0 = h1; h1 = h2; h2 = h3; h3 = hnew;
        b_1 = b_0;  b_0 = bnew;
        bl_1 = bl_0; bl_0 = blnew;
        br_1 = br_0; br_0 = brnew;
        m_1 = m_0;  m_0 = mnew;
        ml_1 = ml_0; ml_0 = mlnew;
        mr_1 = mr_0; mr_0 = mrnew;
        gxp = gx; gyp = gy;
    }
}

__global__ __launch_bounds__(256, 4)
void canny_stream(const float* __restrict__ data, float* __restrict__ out) {
    const int lane = threadIdx.x & 63;
    // XCD-aware swizzle (R11, kept): blocks with equal blockIdx%8 -> one XCD;
    // each XCD owns 2 batches walked band-sequentially for L2 halo locality.
    const int xcd = blockIdx.x & 7;
    const int seq = blockIdx.x >> 3;
    const int lw  = (seq << 2) | (threadIdx.x >> 6);
    const int wc   = lw % NWC;
    const int t    = lw / NWC;
    const int band = t & (NBAND - 1);
    const int bat  = (xcd << 1) | (t >> 5);

    const int c0 = OUTW * wc - 4;
    const int y0 = band * RB;

    const size_t plane = (size_t)(IMH * IMW);
    const float* p0 = data + (size_t)bat * 3 * plane;
    const float* p1 = p0 + plane;
    const float* p2 = p1 + plane;
    float* outp = out + (size_t)bat * plane;

    const bool yb = (band == 0) || (band == NBAND - 1);
    const bool xb = (wc == 0) || (wc == NWC - 1);
    if (yb) {
        if (xb) run_band<true, true >(p0, p1, p2, outp, y0, c0, lane);
        else    run_band<true, false>(p0, p1, p2, outp, y0, c0, lane);
    } else {
        if (xb) run_band<false, true >(p0, p1, p2, outp, y0, c0, lane);
        else    run_band<false, false>(p0, p1, p2, outp, y0, c0, lane);
    }
}

extern "C" void kernel_launch(void* const* d_in, const int* in_sizes, int n_in,
                              void* d_out, int out_size, void* d_ws, size_t ws_size,
                              hipStream_t stream) {
    const float* data = (const float*)d_in[0];
    float* out = (float*)d_out;
    int B = in_sizes[0] / (3 * IMH * IMW);   // 16
    int blocks = (B * NBAND * NWC) / 4;      // 1280 blocks, 5120 waves
    canny_stream<<<blocks, dim3(256, 1, 1), 0, stream>>>(data, out);
}